// Round 5
// baseline (771.264 us; speedup 1.0000x reference)
//
#include <hip/hip_runtime.h>
#include <hip/hip_bf16.h>
#include <math.h>

// Problem constants
#define BATCH 8
#define LTOT 4096
#define DEMB 1024
#define NH 16
#define DH 64
#define CHUNKS 32
#define RPB 128   // rows per block (LTOT / CHUNKS)

// ws layout (float offsets)
#define WS_S     0                          // S      [B][1024][16]
#define WS_SV    (WS_S + BATCH*DEMB*NH)     // sv     [B][16]
#define WS_WQ    (WS_SV + BATCH*NH)         // wq_sw  [B][16][1024]  (transposed+swizzled)
#define WS_C     (WS_WQ + BATCH*DEMB*NH)    // c      [B][16]
#define WS_SPART (WS_C + BATCH*NH)          // Spart  [B*32][1024][16]
#define WS_NEED  ((size_t)(WS_SPART + (size_t)BATCH*CHUNKS*DEMB*NH) * 4)

// Swizzled transposed layout for a [1024][16] matrix staged as [16][1024]:
// logical (h, i) with g=i>>2, lo=i&3 lives at  h*1024 + ((g^h)<<2) + lo.
// float4 read wv4[h*256 + (g^h)] returns logical elements i=4g..4g+3.
// Note (g+128)^h == (g^h)+128 for g<128, h<16.

// ---------------------------------------------------------------------------
// K1: fused v + S partials. 1024 thr, block = (b, 128-row chunk), 1 block/CU.
// Explicit register-ring prefetch + sched_barrier to force deep pipelining
// (R4 showed the scheduler otherwise collapses to ~1 load in flight, VGPR 44).
// ---------------------------------------------------------------------------
__global__ __launch_bounds__(1024, 4) void k1_fused(
    const float* __restrict__ x, const float* __restrict__ Wv,
    const float* __restrict__ bv, float* __restrict__ Spart,
    float* __restrict__ S, float* __restrict__ sv, int direct) {
  __shared__ float wv_sw[DEMB * NH];   // 64 KB
  __shared__ float vt[RPB * NH];       // 8 KB
  __shared__ float sv_red[1024];       // 4 KB

  const int b = blockIdx.x >> 5;
  const int chunk = blockIdx.x & 31;
  const int l0 = chunk * RPB;
  const int t = threadIdx.x;

  // ---- stage Wv[1024][16] -> transposed+swizzled LDS (thread t = row t)
  {
    const float4* wrow = (const float4*)&Wv[(size_t)t * NH];
    const float4 r0 = wrow[0], r1 = wrow[1], r2 = wrow[2], r3 = wrow[3];
    const float vals[16] = {r0.x, r0.y, r0.z, r0.w, r1.x, r1.y, r1.z, r1.w,
                            r2.x, r2.y, r2.z, r2.w, r3.x, r3.y, r3.z, r3.w};
    const int g = t >> 2, lo = t & 3;
    #pragma unroll
    for (int h = 0; h < 16; ++h)
      wv_sw[h * DEMB + (((g ^ h) << 2) + lo)] = vals[h];
  }
  __syncthreads();

  // ---- phase A: thread (rp=t>>4, h=t&15) computes v for rows 2rp, 2rp+1.
  {
    const int h = t & 15;
    const int rp = t >> 4;   // 0..63
    const float4* xA = (const float4*)(x + ((size_t)b * LTOT + l0 + 2 * rp) * DEMB);
    const float4* xB = xA + 256;
    const float4* wv4 = (const float4*)&wv_sw[h * DEMB];
    float cA0 = 0.f, cA1 = 0.f, cB0 = 0.f, cB1 = 0.f;

    float4 rA0[4], rA1[4], rB0[4], rB1[4];   // global rings, depth 4
    float4 rW0[2], rW1[2];                   // LDS ring, depth 2
    #pragma unroll
    for (int s = 0; s < 4; ++s) {
      rA0[s] = xA[s]; rA1[s] = xA[s + 128];
      rB0[s] = xB[s]; rB1[s] = xB[s + 128];
    }
    #pragma unroll
    for (int s = 0; s < 2; ++s) {
      rW0[s] = wv4[s ^ h]; rW1[s] = wv4[(s ^ h) + 128];
    }

    #pragma unroll 4
    for (int g = 0; g < 124; ++g) {
      const int s = g & 3, sw = g & 1;
      const float4 w0 = rW0[sw], w1 = rW1[sw];
      const float4 a0 = rA0[s], a1 = rA1[s], d0 = rB0[s], d1 = rB1[s];
      cA0 += a0.x * w0.x + a0.y * w0.y + a0.z * w0.z + a0.w * w0.w;
      cA1 += a1.x * w1.x + a1.y * w1.y + a1.z * w1.z + a1.w * w1.w;
      cB0 += d0.x * w0.x + d0.y * w0.y + d0.z * w0.z + d0.w * w0.w;
      cB1 += d1.x * w1.x + d1.y * w1.y + d1.z * w1.z + d1.w * w1.w;
      rW0[sw] = wv4[(g + 2) ^ h]; rW1[sw] = wv4[((g + 2) ^ h) + 128];
      rA0[s] = xA[g + 4]; rA1[s] = xA[g + 4 + 128];
      rB0[s] = xB[g + 4]; rB1[s] = xB[g + 4 + 128];
      __builtin_amdgcn_sched_barrier(0);
    }
    #pragma unroll
    for (int g = 124; g < 128; ++g) {
      const int s = g & 3, sw = g & 1;
      const float4 w0 = rW0[sw], w1 = rW1[sw];
      const float4 a0 = rA0[s], a1 = rA1[s], d0 = rB0[s], d1 = rB1[s];
      cA0 += a0.x * w0.x + a0.y * w0.y + a0.z * w0.z + a0.w * w0.w;
      cA1 += a1.x * w1.x + a1.y * w1.y + a1.z * w1.z + a1.w * w1.w;
      cB0 += d0.x * w0.x + d0.y * w0.y + d0.z * w0.z + d0.w * w0.w;
      cB1 += d1.x * w1.x + d1.y * w1.y + d1.z * w1.z + d1.w * w1.w;
      if (g < 126) {
        rW0[sw] = wv4[(g + 2) ^ h]; rW1[sw] = wv4[((g + 2) ^ h) + 128];
      }
      __builtin_amdgcn_sched_barrier(0);
    }

    const float bvh = bv[h];
    const float v0 = bvh + cA0 + cA1;
    const float v1 = bvh + cB0 + cB1;
    vt[(2 * rp) * NH + h] = v0;
    vt[(2 * rp + 1) * NH + h] = v1;
    sv_red[t] = v0 + v1;
  }
  __syncthreads();

  // ---- phase B: thread (i4=t>>2, hg=t&3); streams l and l+64, ring depth 4.
  {
    const int hg = t & 3;
    const int i4 = t >> 2;   // 0..255
    const float4* xb4 = (const float4*)(x + ((size_t)b * LTOT + l0) * DEMB);
    const float4* vt4 = (const float4*)vt;
    float4 accA = {0, 0, 0, 0}, accB = accA, accC = accA, accD = accA;
    float4 acc2A = {0, 0, 0, 0}, acc2B = acc2A, acc2C = acc2A, acc2D = acc2A;

    float4 rx0[4], rx1[4];   // global rings
    float4 rv0[2], rv1[2];   // LDS rings
    #pragma unroll
    for (int s = 0; s < 4; ++s) {
      rx0[s] = xb4[s * 256 + i4];
      rx1[s] = xb4[(s + 64) * 256 + i4];
    }
    #pragma unroll
    for (int s = 0; s < 2; ++s) {
      rv0[s] = vt4[s * 4 + hg];
      rv1[s] = vt4[(s + 64) * 4 + hg];
    }

    #pragma unroll 4
    for (int l = 0; l < 60; ++l) {
      const int s = l & 3, sw = l & 1;
      const float4 xv0 = rx0[s], vv0 = rv0[sw];
      const float4 xv1 = rx1[s], vv1 = rv1[sw];
      accA.x += xv0.x * vv0.x; accA.y += xv0.x * vv0.y; accA.z += xv0.x * vv0.z; accA.w += xv0.x * vv0.w;
      accB.x += xv0.y * vv0.x; accB.y += xv0.y * vv0.y; accB.z += xv0.y * vv0.z; accB.w += xv0.y * vv0.w;
      accC.x += xv0.z * vv0.x; accC.y += xv0.z * vv0.y; accC.z += xv0.z * vv0.z; accC.w += xv0.z * vv0.w;
      accD.x += xv0.w * vv0.x; accD.y += xv0.w * vv0.y; accD.z += xv0.w * vv0.z; accD.w += xv0.w * vv0.w;
      acc2A.x += xv1.x * vv1.x; acc2A.y += xv1.x * vv1.y; acc2A.z += xv1.x * vv1.z; acc2A.w += xv1.x * vv1.w;
      acc2B.x += xv1.y * vv1.x; acc2B.y += xv1.y * vv1.y; acc2B.z += xv1.y * vv1.z; acc2B.w += xv1.y * vv1.w;
      acc2C.x += xv1.z * vv1.x; acc2C.y += xv1.z * vv1.y; acc2C.z += xv1.z * vv1.z; acc2C.w += xv1.z * vv1.w;
      acc2D.x += xv1.w * vv1.x; acc2D.y += xv1.w * vv1.y; acc2D.z += xv1.w * vv1.z; acc2D.w += xv1.w * vv1.w;
      rv0[sw] = vt4[(l + 2) * 4 + hg];
      rv1[sw] = vt4[(l + 2 + 64) * 4 + hg];
      rx0[s] = xb4[(l + 4) * 256 + i4];
      rx1[s] = xb4[(l + 4 + 64) * 256 + i4];
      __builtin_amdgcn_sched_barrier(0);
    }
    #pragma unroll
    for (int l = 60; l < 64; ++l) {
      const int s = l & 3, sw = l & 1;
      const float4 xv0 = rx0[s], vv0 = rv0[sw];
      const float4 xv1 = rx1[s], vv1 = rv1[sw];
      accA.x += xv0.x * vv0.x; accA.y += xv0.x * vv0.y; accA.z += xv0.x * vv0.z; accA.w += xv0.x * vv0.w;
      accB.x += xv0.y * vv0.x; accB.y += xv0.y * vv0.y; accB.z += xv0.y * vv0.z; accB.w += xv0.y * vv0.w;
      accC.x += xv0.z * vv0.x; accC.y += xv0.z * vv0.y; accC.z += xv0.z * vv0.z; accC.w += xv0.z * vv0.w;
      accD.x += xv0.w * vv0.x; accD.y += xv0.w * vv0.y; accD.z += xv0.w * vv0.z; accD.w += xv0.w * vv0.w;
      acc2A.x += xv1.x * vv1.x; acc2A.y += xv1.x * vv1.y; acc2A.z += xv1.x * vv1.z; acc2A.w += xv1.x * vv1.w;
      acc2B.x += xv1.y * vv1.x; acc2B.y += xv1.y * vv1.y; acc2B.z += xv1.y * vv1.z; acc2B.w += xv1.y * vv1.w;
      acc2C.x += xv1.z * vv1.x; acc2C.y += xv1.z * vv1.y; acc2C.z += xv1.z * vv1.z; acc2C.w += xv1.z * vv1.w;
      acc2D.x += xv1.w * vv1.x; acc2D.y += xv1.w * vv1.y; acc2D.z += xv1.w * vv1.z; acc2D.w += xv1.w * vv1.w;
      if (l < 62) {
        rv0[sw] = vt4[(l + 2) * 4 + hg];
        rv1[sw] = vt4[(l + 2 + 64) * 4 + hg];
      }
      __builtin_amdgcn_sched_barrier(0);
    }

    accA.x += acc2A.x; accA.y += acc2A.y; accA.z += acc2A.z; accA.w += acc2A.w;
    accB.x += acc2B.x; accB.y += acc2B.y; accB.z += acc2B.z; accB.w += acc2B.w;
    accC.x += acc2C.x; accC.y += acc2C.y; accC.z += acc2C.z; accC.w += acc2C.w;
    accD.x += acc2D.x; accD.y += acc2D.y; accD.z += acc2D.z; accD.w += acc2D.w;

    const int col0 = i4 << 2;
    if (direct) {
      float* dst = Spart + ((size_t)blockIdx.x << 14);
      *(float4*)&dst[(col0 + 0) * NH + hg * 4] = accA;
      *(float4*)&dst[(col0 + 1) * NH + hg * 4] = accB;
      *(float4*)&dst[(col0 + 2) * NH + hg * 4] = accC;
      *(float4*)&dst[(col0 + 3) * NH + hg * 4] = accD;
    } else {
      float* Sb = S + ((size_t)b << 14);
      const float4 av[4] = {accA, accB, accC, accD};
      #pragma unroll
      for (int c = 0; c < 4; ++c) {
        atomicAdd(&Sb[(col0 + c) * NH + hg * 4 + 0], av[c].x);
        atomicAdd(&Sb[(col0 + c) * NH + hg * 4 + 1], av[c].y);
        atomicAdd(&Sb[(col0 + c) * NH + hg * 4 + 2], av[c].z);
        atomicAdd(&Sb[(col0 + c) * NH + hg * 4 + 3], av[c].w);
      }
    }
  }

  // ---- sv reduction
  if (t < 16) {
    float s = 0.f;
    #pragma unroll
    for (int rr = 0; rr < 64; ++rr) s += sv_red[rr * 16 + t];
    atomicAdd(&sv[b * NH + t], s);
  }
}

// ---------------------------------------------------------------------------
// K1b: reduce 32 chunk-partials -> S.  256 blocks x 256 thr.
// ---------------------------------------------------------------------------
__global__ __launch_bounds__(256) void k1b_reduce(
    const float* __restrict__ Spart, float* __restrict__ S) {
  const int b = blockIdx.x >> 5;
  const int seg = blockIdx.x & 31;
  #pragma unroll
  for (int k = 0; k < 2; ++k) {
    const int idx = seg * 512 + k * 256 + threadIdx.x;
    float s = 0.f;
    #pragma unroll 8
    for (int c = 0; c < CHUNKS; ++c)
      s += Spart[((size_t)(b * CHUNKS + c) << 14) + idx];
    S[((size_t)b << 14) + idx] = s;
  }
}

// ---------------------------------------------------------------------------
// K2: ktv + wq_eff (written transposed+swizzled) + c. grid B*NH, 1024 thr.
// ---------------------------------------------------------------------------
__global__ __launch_bounds__(1024) void k2_ktv_wq(
    const float* __restrict__ Wq, const float* __restrict__ bq,
    const float* __restrict__ Wk, const float* __restrict__ bk,
    const float* __restrict__ S, const float* __restrict__ sv,
    float* __restrict__ wq_sw, float* __restrict__ cvec) {
  __shared__ float part[16][DH];
  __shared__ float ktv[DH];
  const int b = blockIdx.x >> 4;
  const int h = blockIdx.x & 15;
  const int t = threadIdx.x;
  const float* Sb = S + ((size_t)b << 14);

  const int d = t & 63, seg = t >> 6;   // 16 segs x 64 i
  float p = 0.f;
  #pragma unroll 4
  for (int i = seg * 64; i < seg * 64 + 64; ++i)
    p += Wk[(size_t)i * DEMB + h * DH + d] * Sb[i * NH + h];
  part[seg][d] = p;
  __syncthreads();
  if (t < 64) {
    float s = 0.f;
    #pragma unroll
    for (int k = 0; k < 16; ++k) s += part[k][t];
    s += bk[h * DH + t] * sv[b * NH + h];
    ktv[t] = s;
  }
  __syncthreads();

  {
    const int i = t;
    const float* wrow = &Wq[(size_t)i * DEMB + h * DH];
    float s0 = 0.f, s1 = 0.f;
    #pragma unroll
    for (int dd = 0; dd < DH; dd += 8) {
      const float4 w4 = *(const float4*)&wrow[dd];
      const float4 w5 = *(const float4*)&wrow[dd + 4];
      s0 += w4.x * ktv[dd] + w4.y * ktv[dd + 1] + w4.z * ktv[dd + 2] + w4.w * ktv[dd + 3];
      s1 += w5.x * ktv[dd + 4] + w5.y * ktv[dd + 5] + w5.z * ktv[dd + 6] + w5.w * ktv[dd + 7];
    }
    wq_sw[(size_t)b * DEMB * NH + h * DEMB + ((((i >> 2) ^ h) << 2) + (i & 3))] = s0 + s1;
  }
  if (t == 0) {
    float s = 0.f;
    for (int dd = 0; dd < DH; ++dd) s += bq[h * DH + dd] * ktv[dd];
    cvec[b * NH + h] = s;
  }
}

// ---------------------------------------------------------------------------
// K3: z = (x . wq_eff + c)/8 -> sigmoid -> mask. Same pipelined dot as phase A.
// ---------------------------------------------------------------------------
__global__ __launch_bounds__(1024, 4) void k3_z_sigmoid(
    const float* __restrict__ x, const int* __restrict__ mask,
    const float* __restrict__ wq_sw_g, const float* __restrict__ cvec,
    float* __restrict__ out) {
  __shared__ float wq_sw[DEMB * NH];   // 64 KB (already swizzled in global)
  __shared__ float c_lds[NH];

  const int b = blockIdx.x >> 5;
  const int chunk = blockIdx.x & 31;
  const int l0 = chunk * RPB;
  const int t = threadIdx.x;

  const float4* src = (const float4*)(wq_sw_g + (size_t)b * DEMB * NH);
  float4* dst = (float4*)wq_sw;
  #pragma unroll
  for (int j = t; j < DEMB * NH / 4; j += 1024) dst[j] = src[j];
  if (t < 16) c_lds[t] = cvec[b * NH + t];
  __syncthreads();

  const int h = t & 15;
  const int rp = t >> 4;
  const int l = l0 + 2 * rp;
  const float4* xA = (const float4*)(x + ((size_t)b * LTOT + l) * DEMB);
  const float4* xB = xA + 256;
  const float4* wq4 = (const float4*)&wq_sw[h * DEMB];
  float cA0 = 0.f, cA1 = 0.f, cB0 = 0.f, cB1 = 0.f;

  float4 rA0[4], rA1[4], rB0[4], rB1[4];
  float4 rW0[2], rW1[2];
  #pragma unroll
  for (int s = 0; s < 4; ++s) {
    rA0[s] = xA[s]; rA1[s] = xA[s + 128];
    rB0[s] = xB[s]; rB1[s] = xB[s + 128];
  }
  #pragma unroll
  for (int s = 0; s < 2; ++s) {
    rW0[s] = wq4[s ^ h]; rW1[s] = wq4[(s ^ h) + 128];
  }

  #pragma unroll 4
  for (int g = 0; g < 124; ++g) {
    const int s = g & 3, sw = g & 1;
    const float4 w0 = rW0[sw], w1 = rW1[sw];
    const float4 a0 = rA0[s], a1 = rA1[s], d0 = rB0[s], d1 = rB1[s];
    cA0 += a0.x * w0.x + a0.y * w0.y + a0.z * w0.z + a0.w * w0.w;
    cA1 += a1.x * w1.x + a1.y * w1.y + a1.z * w1.z + a1.w * w1.w;
    cB0 += d0.x * w0.x + d0.y * w0.y + d0.z * w0.z + d0.w * w0.w;
    cB1 += d1.x * w1.x + d1.y * w1.y + d1.z * w1.z + d1.w * w1.w;
    rW0[sw] = wq4[(g + 2) ^ h]; rW1[sw] = wq4[((g + 2) ^ h) + 128];
    rA0[s] = xA[g + 4]; rA1[s] = xA[g + 4 + 128];
    rB0[s] = xB[g + 4]; rB1[s] = xB[g + 4 + 128];
    __builtin_amdgcn_sched_barrier(0);
  }
  #pragma unroll
  for (int g = 124; g < 128; ++g) {
    const int s = g & 3, sw = g & 1;
    const float4 w0 = rW0[sw], w1 = rW1[sw];
    const float4 a0 = rA0[s], a1 = rA1[s], d0 = rB0[s], d1 = rB1[s];
    cA0 += a0.x * w0.x + a0.y * w0.y + a0.z * w0.z + a0.w * w0.w;
    cA1 += a1.x * w1.x + a1.y * w1.y + a1.z * w1.z + a1.w * w1.w;
    cB0 += d0.x * w0.x + d0.y * w0.y + d0.z * w0.z + d0.w * w0.w;
    cB1 += d1.x * w1.x + d1.y * w1.y + d1.z * w1.z + d1.w * w1.w;
    if (g < 126) {
      rW0[sw] = wq4[(g + 2) ^ h]; rW1[sw] = wq4[((g + 2) ^ h) + 128];
    }
    __builtin_amdgcn_sched_barrier(0);
  }

  const float cb = c_lds[h];
  const float z0 = (cb + cA0 + cA1) * 0.125f;
  const float z1 = (cb + cB0 + cB1) * 0.125f;
  float p0 = 1.f / (1.f + __expf(-z0));
  float p1 = 1.f / (1.f + __expf(-z1));
  if (mask[b * LTOT + l] == 0) p0 = 0.f;
  if (mask[b * LTOT + l + 1] == 0) p1 = 0.f;
  float* orow = out + ((size_t)(b * NH + h)) * LTOT;
  orow[l] = p0;
  orow[l + 1] = p1;
}

extern "C" void kernel_launch(void* const* d_in, const int* in_sizes, int n_in,
                              void* d_out, int out_size, void* d_ws, size_t ws_size,
                              hipStream_t stream) {
  const float* x  = (const float*)d_in[0];
  const int* mask = (const int*)d_in[1];
  const float* Wq = (const float*)d_in[2];
  const float* bq = (const float*)d_in[3];
  const float* Wk = (const float*)d_in[4];
  const float* bk = (const float*)d_in[5];
  const float* Wv = (const float*)d_in[6];
  const float* bv = (const float*)d_in[7];
  float* out = (float*)d_out;
  float* ws = (float*)d_ws;

  float* S      = ws + WS_S;
  float* sv     = ws + WS_SV;
  float* wq_sw  = ws + WS_WQ;
  float* cvec   = ws + WS_C;
  float* Spart  = ws + WS_SPART;

  const int direct = (ws_size >= WS_NEED) ? 1 : 0;

  hipMemsetAsync(sv, 0, BATCH * NH * sizeof(float), stream);
  if (!direct) hipMemsetAsync(S, 0, (size_t)BATCH * DEMB * NH * sizeof(float), stream);

  k1_fused<<<dim3(BATCH * CHUNKS), dim3(1024), 0, stream>>>(x, Wv, bv, Spart, S, sv, direct);
  if (direct)
    k1b_reduce<<<dim3(BATCH * CHUNKS), dim3(256), 0, stream>>>(Spart, S);
  k2_ktv_wq<<<dim3(BATCH * NH), dim3(1024), 0, stream>>>(Wq, bq, Wk, bk, S, sv, wq_sw, cvec);
  k3_z_sigmoid<<<dim3(BATCH * CHUNKS), dim3(1024), 0, stream>>>(x, mask, wq_sw, cvec, out);
}

// Round 6
// 499.923 us; speedup vs baseline: 1.5428x; 1.5428x over previous
//
#include <hip/hip_runtime.h>
#include <hip/hip_bf16.h>
#include <math.h>

// Problem constants
#define BATCH 8
#define LTOT 4096
#define DEMB 1024
#define NH 16
#define DH 64
#define CHUNKS 32
#define RPB 128   // rows per block (LTOT / CHUNKS)

// ws layout (float offsets). S / wq are h-major (transposed) now.
#define WS_S     0                          // St     [B][16][1024]
#define WS_SV    (WS_S + BATCH*DEMB*NH)     // sv     [B][16]
#define WS_WQ    (WS_SV + BATCH*NH)         // wqt    [B][16][1024]
#define WS_C     (WS_WQ + BATCH*DEMB*NH)    // c      [B][16]
#define WS_SPART (WS_C + BATCH*NH)          // SpartT [B*32][16][1024]
#define WS_NEED  ((size_t)(WS_SPART + (size_t)BATCH*CHUNKS*DEMB*NH) * 4)

// Lane mapping for the row-dot phases (K1 phase A, K3):
//   w = t>>6 (wave), lane = t&63
//   h  = ((w&7)<<1) | (lane&1)          -> wave covers an h-PAIR
//   rp = ((w>>3)<<5) | (lane>>1)        -> 32 row-pairs per wave
// Each x-load instruction touches 32 distinct cache lines (MLP fix);
// W reads are wave-uniform (2 addrs) -> LDS broadcast, conflict-free.

// ---------------------------------------------------------------------------
// K1: fused v + S partials. grid = B*CHUNKS = 256, 1024 thr, 1 block/CU.
// ---------------------------------------------------------------------------
__global__ __launch_bounds__(1024, 4) void k1_fused(
    const float* __restrict__ x, const float* __restrict__ Wv,
    const float* __restrict__ bv, float* __restrict__ Spart,
    float* __restrict__ S, float* __restrict__ sv, int direct) {
  __shared__ float wvt[NH * DEMB];   // [h][i] transposed, 64 KB
  __shared__ float vth[NH * RPB];    // [h][l], 8 KB
  __shared__ float sv_red[1024];     // 4 KB

  const int b = blockIdx.x >> 5;
  const int chunk = blockIdx.x & 31;
  const int l0 = chunk * RPB;
  const int t = threadIdx.x;

  // ---- stage Wv[1024][16] -> wvt[16][1024] (transpose; coalesced read,
  //      conflict-free scalar writes: lanes consecutive i per h)
  {
    const float4* wrow = (const float4*)&Wv[(size_t)t * NH];
    const float4 r0 = wrow[0], r1 = wrow[1], r2 = wrow[2], r3 = wrow[3];
    const float vals[16] = {r0.x, r0.y, r0.z, r0.w, r1.x, r1.y, r1.z, r1.w,
                            r2.x, r2.y, r2.z, r2.w, r3.x, r3.y, r3.z, r3.w};
    #pragma unroll
    for (int h = 0; h < 16; ++h) wvt[h * DEMB + t] = vals[h];
  }
  __syncthreads();

  // ---- phase A: v[row, h] for rows 2rp, 2rp+1
  {
    const int w = t >> 6, lane = t & 63;
    const int h = ((w & 7) << 1) | (lane & 1);
    const int rp = ((w >> 3) << 5) | (lane >> 1);
    const float4* xA = (const float4*)(x + ((size_t)b * LTOT + l0 + 2 * rp) * DEMB);
    const float4* xB = xA + 256;
    const float4* wv4 = (const float4*)&wvt[h * DEMB];
    float cA0 = 0.f, cA1 = 0.f, cB0 = 0.f, cB1 = 0.f;
    #pragma unroll 4
    for (int g = 0; g < 128; ++g) {
      const float4 w0 = wv4[g];
      const float4 w1 = wv4[g + 128];
      const float4 a0 = xA[g];
      const float4 a1 = xA[g + 128];
      const float4 d0 = xB[g];
      const float4 d1 = xB[g + 128];
      cA0 += a0.x * w0.x + a0.y * w0.y + a0.z * w0.z + a0.w * w0.w;
      cA1 += a1.x * w1.x + a1.y * w1.y + a1.z * w1.z + a1.w * w1.w;
      cB0 += d0.x * w0.x + d0.y * w0.y + d0.z * w0.z + d0.w * w0.w;
      cB1 += d1.x * w1.x + d1.y * w1.y + d1.z * w1.z + d1.w * w1.w;
    }
    const float bvh = bv[h];
    const float v0 = bvh + cA0 + cA1;
    const float v1 = bvh + cB0 + cB1;
    *(float2*)&vth[h * RPB + 2 * rp] = make_float2(v0, v1);
    sv_red[t] = v0 + v1;
  }
  __syncthreads();

  // ---- phase B: S^T accumulate. wave-uniform hg = t>>8; i4 = t&255.
  //      x: 1 KB contiguous per wave-instr; v: whole-wave broadcast b32.
  {
    const int hg = t >> 8;    // 0..3
    const int i4 = t & 255;
    const float4* xb4 = (const float4*)(x + ((size_t)b * LTOT + l0) * DEMB);
    float4 acc0 = {0, 0, 0, 0}, acc1 = acc0, acc2 = acc0, acc3 = acc0;
    #pragma unroll 4
    for (int l = 0; l < RPB; ++l) {
      const float4 xv = xb4[l * 256 + i4];
      const float v0 = vth[(4 * hg + 0) * RPB + l];
      const float v1 = vth[(4 * hg + 1) * RPB + l];
      const float v2 = vth[(4 * hg + 2) * RPB + l];
      const float v3 = vth[(4 * hg + 3) * RPB + l];
      acc0.x += xv.x * v0; acc0.y += xv.y * v0; acc0.z += xv.z * v0; acc0.w += xv.w * v0;
      acc1.x += xv.x * v1; acc1.y += xv.y * v1; acc1.z += xv.z * v1; acc1.w += xv.w * v1;
      acc2.x += xv.x * v2; acc2.y += xv.y * v2; acc2.z += xv.z * v2; acc2.w += xv.w * v2;
      acc3.x += xv.x * v3; acc3.y += xv.y * v3; acc3.z += xv.z * v3; acc3.w += xv.w * v3;
    }
    if (direct) {
      // SpartT[block][h][i]: coalesced float4 stores (lanes i4 consecutive)
      float* dst = Spart + ((size_t)blockIdx.x << 14);
      *(float4*)&dst[(4 * hg + 0) * DEMB + 4 * i4] = acc0;
      *(float4*)&dst[(4 * hg + 1) * DEMB + 4 * i4] = acc1;
      *(float4*)&dst[(4 * hg + 2) * DEMB + 4 * i4] = acc2;
      *(float4*)&dst[(4 * hg + 3) * DEMB + 4 * i4] = acc3;
    } else {
      float* Sb = S + ((size_t)b << 14);
      const float4 av[4] = {acc0, acc1, acc2, acc3};
      #pragma unroll
      for (int j = 0; j < 4; ++j) {
        atomicAdd(&Sb[(4 * hg + j) * DEMB + 4 * i4 + 0], av[j].x);
        atomicAdd(&Sb[(4 * hg + j) * DEMB + 4 * i4 + 1], av[j].y);
        atomicAdd(&Sb[(4 * hg + j) * DEMB + 4 * i4 + 2], av[j].z);
        atomicAdd(&Sb[(4 * hg + j) * DEMB + 4 * i4 + 3], av[j].w);
      }
    }
  }

  // ---- sv reduction (sv_red stable since the phase-B barrier)
  if (t < 16) {
    const int h = t;
    float s = 0.f;
    #pragma unroll
    for (int w2 = 0; w2 < 2; ++w2) {
      const int base = (((h >> 1) + 8 * w2) << 6) + (h & 1);
      #pragma unroll
      for (int j = 0; j < 32; ++j) s += sv_red[base + 2 * j];
    }
    atomicAdd(&sv[b * NH + h], s);
  }
}

// ---------------------------------------------------------------------------
// K1b: reduce 32 chunk-partials -> St.  256 blocks x 256 thr.
// ---------------------------------------------------------------------------
__global__ __launch_bounds__(256) void k1b_reduce(
    const float* __restrict__ Spart, float* __restrict__ S) {
  const int b = blockIdx.x >> 5;
  const int seg = blockIdx.x & 31;
  #pragma unroll
  for (int k = 0; k < 2; ++k) {
    const int idx = seg * 512 + k * 256 + threadIdx.x;
    float s = 0.f;
    #pragma unroll 8
    for (int c = 0; c < CHUNKS; ++c)
      s += Spart[((size_t)(b * CHUNKS + c) << 14) + idx];
    S[((size_t)b << 14) + idx] = s;
  }
}

// ---------------------------------------------------------------------------
// K2: ktv + wqt (h-major) + c. grid B*NH, 1024 thr.
// St reads are wave-broadcast; Wk reads coalesced; wqt store coalesced.
// ---------------------------------------------------------------------------
__global__ __launch_bounds__(1024) void k2_ktv_wq(
    const float* __restrict__ Wq, const float* __restrict__ bq,
    const float* __restrict__ Wk, const float* __restrict__ bk,
    const float* __restrict__ S, const float* __restrict__ sv,
    float* __restrict__ wqt, float* __restrict__ cvec) {
  __shared__ float part[16][DH];
  __shared__ float ktv[DH];
  const int b = blockIdx.x >> 4;
  const int h = blockIdx.x & 15;
  const int t = threadIdx.x;
  const float* Sth = S + ((size_t)b << 14) + h * DEMB;

  const int d = t & 63, seg = t >> 6;   // 16 segs x 64 i
  float p = 0.f;
  #pragma unroll 4
  for (int i = seg * 64; i < seg * 64 + 64; ++i)
    p += Wk[(size_t)i * DEMB + h * DH + d] * Sth[i];
  part[seg][d] = p;
  __syncthreads();
  if (t < 64) {
    float s = 0.f;
    #pragma unroll
    for (int k = 0; k < 16; ++k) s += part[k][t];
    s += bk[h * DH + t] * sv[b * NH + h];
    ktv[t] = s;
  }
  __syncthreads();

  {
    const int i = t;
    const float* wrow = &Wq[(size_t)i * DEMB + h * DH];
    float s0 = 0.f, s1 = 0.f;
    #pragma unroll
    for (int dd = 0; dd < DH; dd += 8) {
      const float4 w4 = *(const float4*)&wrow[dd];
      const float4 w5 = *(const float4*)&wrow[dd + 4];
      s0 += w4.x * ktv[dd] + w4.y * ktv[dd + 1] + w4.z * ktv[dd + 2] + w4.w * ktv[dd + 3];
      s1 += w5.x * ktv[dd + 4] + w5.y * ktv[dd + 5] + w5.z * ktv[dd + 6] + w5.w * ktv[dd + 7];
    }
    wqt[((size_t)b << 14) + h * DEMB + i] = s0 + s1;
  }
  if (t == 0) {
    float s = 0.f;
    for (int dd = 0; dd < DH; ++dd) s += bq[h * DH + dd] * ktv[dd];
    cvec[b * NH + h] = s;
  }
}

// ---------------------------------------------------------------------------
// K3: z = (x . wq_eff + c)/8 -> sigmoid -> mask. Same mapping as K1 phase A.
// ---------------------------------------------------------------------------
__global__ __launch_bounds__(1024, 4) void k3_z_sigmoid(
    const float* __restrict__ x, const int* __restrict__ mask,
    const float* __restrict__ wqt_g, const float* __restrict__ cvec,
    float* __restrict__ out) {
  __shared__ float wqt[NH * DEMB];   // 64 KB, already h-major in global
  __shared__ float c_lds[NH];

  const int b = blockIdx.x >> 5;
  const int chunk = blockIdx.x & 31;
  const int l0 = chunk * RPB;
  const int t = threadIdx.x;

  const float4* src = (const float4*)(wqt_g + ((size_t)b << 14));
  float4* dst = (float4*)wqt;
  #pragma unroll
  for (int j = t; j < DEMB * NH / 4; j += 1024) dst[j] = src[j];
  if (t < 16) c_lds[t] = cvec[b * NH + t];
  __syncthreads();

  const int w = t >> 6, lane = t & 63;
  const int h = ((w & 7) << 1) | (lane & 1);
  const int rp = ((w >> 3) << 5) | (lane >> 1);
  const int l = l0 + 2 * rp;
  const float4* xA = (const float4*)(x + ((size_t)b * LTOT + l) * DEMB);
  const float4* xB = xA + 256;
  const float4* wq4 = (const float4*)&wqt[h * DEMB];
  float cA0 = 0.f, cA1 = 0.f, cB0 = 0.f, cB1 = 0.f;
  #pragma unroll 4
  for (int g = 0; g < 128; ++g) {
    const float4 w0 = wq4[g];
    const float4 w1 = wq4[g + 128];
    const float4 a0 = xA[g];
    const float4 a1 = xA[g + 128];
    const float4 d0 = xB[g];
    const float4 d1 = xB[g + 128];
    cA0 += a0.x * w0.x + a0.y * w0.y + a0.z * w0.z + a0.w * w0.w;
    cA1 += a1.x * w1.x + a1.y * w1.y + a1.z * w1.z + a1.w * w1.w;
    cB0 += d0.x * w0.x + d0.y * w0.y + d0.z * w0.z + d0.w * w0.w;
    cB1 += d1.x * w1.x + d1.y * w1.y + d1.z * w1.z + d1.w * w1.w;
  }
  const float cb = c_lds[h];
  const float z0 = (cb + cA0 + cA1) * 0.125f;
  const float z1 = (cb + cB0 + cB1) * 0.125f;
  float p0 = 1.f / (1.f + __expf(-z0));
  float p1 = 1.f / (1.f + __expf(-z1));
  if (mask[b * LTOT + l] == 0) p0 = 0.f;
  if (mask[b * LTOT + l + 1] == 0) p1 = 0.f;
  float* orow = out + ((size_t)(b * NH + h)) * LTOT;
  *(float2*)&orow[l] = make_float2(p0, p1);
}

extern "C" void kernel_launch(void* const* d_in, const int* in_sizes, int n_in,
                              void* d_out, int out_size, void* d_ws, size_t ws_size,
                              hipStream_t stream) {
  const float* x  = (const float*)d_in[0];
  const int* mask = (const int*)d_in[1];
  const float* Wq = (const float*)d_in[2];
  const float* bq = (const float*)d_in[3];
  const float* Wk = (const float*)d_in[4];
  const float* bk = (const float*)d_in[5];
  const float* Wv = (const float*)d_in[6];
  const float* bv = (const float*)d_in[7];
  float* out = (float*)d_out;
  float* ws = (float*)d_ws;

  float* St     = ws + WS_S;
  float* sv     = ws + WS_SV;
  float* wqt    = ws + WS_WQ;
  float* cvec   = ws + WS_C;
  float* Spart  = ws + WS_SPART;

  const int direct = (ws_size >= WS_NEED) ? 1 : 0;

  hipMemsetAsync(sv, 0, BATCH * NH * sizeof(float), stream);
  if (!direct) hipMemsetAsync(St, 0, (size_t)BATCH * DEMB * NH * sizeof(float), stream);

  k1_fused<<<dim3(BATCH * CHUNKS), dim3(1024), 0, stream>>>(x, Wv, bv, Spart, St, sv, direct);
  if (direct)
    k1b_reduce<<<dim3(BATCH * CHUNKS), dim3(256), 0, stream>>>(Spart, St);
  k2_ktv_wq<<<dim3(BATCH * NH), dim3(1024), 0, stream>>>(Wq, bq, Wk, bk, St, sv, wqt, cvec);
  k3_z_sigmoid<<<dim3(BATCH * CHUNKS), dim3(1024), 0, stream>>>(x, mask, wqt, cvec, out);
}